// Round 2
// baseline (83.837 us; speedup 1.0000x reference)
//
#include <hip/hip_runtime.h>

// ConcentrationLoss: pred,target [B=16,C=10,H=512,W=512] f32 -> scalar f32.
// One fused streaming pass (moment expansion of distance field) + tiny finalize.

#define BB 16
#define CC 10
#define HH 512
#define WW 512
#define HW (HH * WW)          // 262144 elements per slice
#define SLICES (BB * CC)      // 160
#define THREADS 256
#define NACC 8

template <int CH>
__global__ __launch_bounds__(THREADS) void conc_pass1(
    const float* __restrict__ pred,
    const float* __restrict__ target,
    float* __restrict__ ws) {
  constexpr int V4C = HW / 4 / CH;      // float4 per chunk
  constexpr int VPT = V4C / THREADS;    // float4 per thread (CH=64 -> 4, CH=16 -> 16)
  const int slice = blockIdx.x / CH;
  const int chunk = blockIdx.x % CH;
  const int tid = threadIdx.x;

  const float4* __restrict__ p4 =
      reinterpret_cast<const float4*>(pred + (size_t)slice * HW) + chunk * V4C;
  const float4* __restrict__ t4 =
      reinterpret_cast<const float4*>(target + (size_t)slice * HW) + chunk * V4C;

  float tm = 0.f, ty = 0.f, tx = 0.f;
  float s0 = 0.f, sy = 0.f, sx = 0.f, syy = 0.f, sxx = 0.f;

  for (int b = 0; b < VPT; b += 4) {
    // issue all 8 loads before any use -> max memory-level parallelism
    float4 tb[4], pb[4];
#pragma unroll
    for (int j = 0; j < 4; ++j) {
      const int v = (b + j) * THREADS + tid;
      tb[j] = t4[v];
      pb[j] = p4[v];
    }
#pragma unroll
    for (int j = 0; j < 4; ++j) {
      const int v = (b + j) * THREADS + tid;
      const int e = (chunk * V4C + v) * 4;     // element index in slice
      const float y  = (float)(e >> 9);        // row (W=512)
      const float x0 = (float)(e & 511);       // col of .x lane (e%4==0)
      const float x1 = x0 + 1.f, x2 = x0 + 2.f, x3 = x0 + 3.f;
      const float4 t = tb[j];
      const float4 p = pb[j];

      const float tsum = (t.x + t.y) + (t.z + t.w);
      tm += tsum;
      ty += tsum * y;
      tx += t.x * x0 + t.y * x1 + t.z * x2 + t.w * x3;

      const float g0 = 1.f / (1.f + __expf(-p.x));
      const float g1 = 1.f / (1.f + __expf(-p.y));
      const float g2 = 1.f / (1.f + __expf(-p.z));
      const float g3 = 1.f / (1.f + __expf(-p.w));
      const float gs = (g0 + g1) + (g2 + g3);
      s0  += gs;
      sy  += gs * y;
      syy += gs * (y * y);
      sx  += g0 * x0 + g1 * x1 + g2 * x2 + g3 * x3;
      sxx += g0 * (x0 * x0) + g1 * (x1 * x1) + g2 * (x2 * x2) + g3 * (x3 * x3);
    }
  }

  // block reduction: wave64 shuffle, then across 4 waves via LDS
  float acc[NACC] = {tm, ty, tx, s0, sy, sx, syy, sxx};
#pragma unroll
  for (int k = 0; k < NACC; ++k) {
    float v = acc[k];
#pragma unroll
    for (int off = 32; off > 0; off >>= 1) v += __shfl_down(v, off, 64);
    acc[k] = v;
  }
  __shared__ float red[4][NACC];
  const int lane = tid & 63, wave = tid >> 6;
  if (lane == 0) {
#pragma unroll
    for (int k = 0; k < NACC; ++k) red[wave][k] = acc[k];
  }
  __syncthreads();
  if (tid == 0) {
    float* out = ws + (size_t)blockIdx.x * NACC;
#pragma unroll
    for (int k = 0; k < NACC; ++k)
      out[k] = red[0][k] + red[1][k] + red[2][k] + red[3][k];
  }
}

// 512 threads = 8 waves; wave w handles slices w, w+8, ...; lane = chunk row.
template <int CH>
__global__ __launch_bounds__(512) void conc_pass2(
    const float* __restrict__ ws, float* __restrict__ out) {
  const int tid = threadIdx.x;
  const int lane = tid & 63, wave = tid >> 6;

  double lsum = 0.0;
  int nvalid = 0;

  for (int s = wave; s < SLICES; s += 8) {
    float m[NACC];
    if (lane < CH) {
      const float4* r =
          reinterpret_cast<const float4*>(ws + ((size_t)s * CH + lane) * NACC);
      const float4 a = r[0], b = r[1];
      m[0] = a.x; m[1] = a.y; m[2] = a.z; m[3] = a.w;
      m[4] = b.x; m[5] = b.y; m[6] = b.z; m[7] = b.w;
    } else {
#pragma unroll
      for (int k = 0; k < NACC; ++k) m[k] = 0.f;
    }
#pragma unroll
    for (int k = 0; k < NACC; ++k) {
      float v = m[k];
#pragma unroll
      for (int off = 32; off > 0; off >>= 1) v += __shfl_xor(v, off, 64);
      m[k] = v;
    }
    if (lane == 0) {
      const double tm = m[0], ty = m[1], tx = m[2];
      const double s0 = m[3], sy = m[4], sx = m[5], syy = m[6], sxx = m[7];
      const bool valid = tm > 0.0;
      const double mass = valid ? tm : 1.0;
      const double cy = ty / mass, cx = tx / mass;
      const double conc =
          syy + sxx - 2.0 * cy * sy - 2.0 * cx * sx + (cy * cy + cx * cx) * s0;
      if (valid) {
        lsum += conc / (double)HW;
        ++nvalid;
      }
    }
  }

  __shared__ double sd[8];
  __shared__ int si[8];
  if (lane == 0) {
    sd[wave] = lsum;
    si[wave] = nvalid;
  }
  __syncthreads();
  if (tid == 0) {
    double t = 0.0;
    int n = 0;
#pragma unroll
    for (int w = 0; w < 8; ++w) {
      t += sd[w];
      n += si[w];
    }
    out[0] = (float)((n > 0) ? (t / (double)n) : 0.0);
  }
}

extern "C" void kernel_launch(void* const* d_in, const int* in_sizes, int n_in,
                              void* d_out, int out_size, void* d_ws, size_t ws_size,
                              hipStream_t stream) {
  const float* pred = (const float*)d_in[0];
  const float* target = (const float*)d_in[1];
  float* ws = (float*)d_ws;
  float* out = (float*)d_out;

  const size_t need64 = (size_t)SLICES * 64 * NACC * sizeof(float);  // 320 KiB
  if (ws_size >= need64) {
    // 10240 blocks = exactly 5 full-GPU residency rounds (2048 co-resident)
    conc_pass1<64><<<SLICES * 64, THREADS, 0, stream>>>(pred, target, ws);
    conc_pass2<64><<<1, 512, 0, stream>>>(ws, out);
  } else {
    conc_pass1<16><<<SLICES * 16, THREADS, 0, stream>>>(pred, target, ws);
    conc_pass2<16><<<1, 512, 0, stream>>>(ws, out);
  }
}